// Round 12
// baseline (209.539 us; speedup 1.0000x reference)
//
#include <hip/hip_runtime.h>

#define N_NODES 2048
#define N_EDGES 65536
#define NV 6
#define C 32
#define BLK 256

// ---------------------------------------------------------------------------
// ws layout (ints then floats): cnt_i[2048] cursor[2048] (16KB memset)
//   rowptr[2049] pad | eid[65536] | h1 h2 h3 [N*32 each]
// No msg buffer (R9 lesson), no sum buffers / atomics in layers 2/3:
// node-centric fused NNConv accumulates messages in registers.
// R11 lesson: reg-W core needs ~185 VGPR -> never cap below (256,2).
// ---------------------------------------------------------------------------

__global__ void hist_kernel(const int* __restrict__ dst, int* __restrict__ cnt) {
    int e = blockIdx.x * blockDim.x + threadIdx.x;
    if (e < N_EDGES) atomicAdd(&cnt[dst[e]], 1);
}

__global__ __launch_bounds__(256) void scan_kernel(const int* __restrict__ cnt,
                                                   int* __restrict__ rowptr) {
    __shared__ int part[256];
    const int tid = threadIdx.x;
    int local[8];
    int s = 0;
#pragma unroll
    for (int k = 0; k < 8; k++) { local[k] = cnt[tid * 8 + k]; s += local[k]; }
    part[tid] = s;
    __syncthreads();
    for (int off = 1; off < 256; off <<= 1) {
        int v = (tid >= off) ? part[tid - off] : 0;
        __syncthreads();
        part[tid] += v;
        __syncthreads();
    }
    int run = part[tid] - s;
#pragma unroll
    for (int k = 0; k < 8; k++) { rowptr[tid * 8 + k] = run; run += local[k]; }
    if (tid == 255) rowptr[2048] = run;
}

__global__ void scatter_kernel(const int* __restrict__ dst, const int* __restrict__ rowptr,
                               int* __restrict__ cursor, int* __restrict__ eid) {
    int e = blockIdx.x * blockDim.x + threadIdx.x;
    if (e < N_EDGES) {
        int d = dst[e];
        int pos = atomicAdd(&cursor[d], 1);
        eid[rowptr[d] + pos] = e;
    }
}

// ---- Layer 1 fused (R8/R9-proven): wave per node, lane = p*32+o.
__global__ __launch_bounds__(BLK) void layer1_kernel(
    const float* __restrict__ x, const float* __restrict__ ea,
    const int* __restrict__ src, const int* __restrict__ rowptr,
    const int* __restrict__ eid,
    const float* __restrict__ W1, const float* __restrict__ b1,
    const float* __restrict__ root1, const float* __restrict__ bias1,
    float* __restrict__ h1) {
    const int lane = threadIdx.x & 63;
    const int o = lane & 31;
    const int p = lane >> 5;
    const int n = blockIdx.x * 4 + (threadIdx.x >> 6);
    float w1r[NV];
#pragma unroll
    for (int v = 0; v < NV; v++) w1r[v] = W1[v * C + o];
    const float b1o = b1[o];
    const int beg = rowptr[n], end = rowptr[n + 1];
    float acc = 0.0f;
    for (int k = beg + p; k < end; k += 2) {
        const int e = eid[k];
        const float xs = x[src[e]];
        const float* eap = ea + e * NV;
        float t = b1o;
#pragma unroll
        for (int v = 0; v < NV; v++) t = fmaf(eap[v], w1r[v], t);
        acc = fmaf(xs, fmaxf(t, 0.0f), acc);
    }
    acc += __shfl_down(acc, 32);
    if (lane < 32) {
        const float inv = 1.0f / fmaxf((float)(end - beg), 1.0f);
        float r = fmaf(acc, inv, bias1[o]);
        r = fmaf(x[n], root1[o], r);
        h1[n * C + o] = fmaxf(r, 0.0f);
    }
}

// ---- Layers 2/3 node-centric fused NNConv: wave per node, no atomics,
// no msg. Inner body = R5/R10-proven reg-W + LDS h-transpose (contiguous
// 1KB b128 write, broadcast b128 reads). All 8 batch-edges share the node,
// so per-edge partials sum into ONE scalar acc; single shfl at node end;
// mean+root+bias+relu fused; one coalesced store. Tail edges: eid index
// clamped (in-bounds), h zero-masked at staging => contribution 0.
__global__ __launch_bounds__(BLK, 2) void nnconv23_kernel(
    const float* __restrict__ hprev,   // [N, 32]
    const float* __restrict__ ea,      // [E, 6]
    const int* __restrict__ src,
    const int* __restrict__ rowptr,
    const int* __restrict__ eid,
    const float* __restrict__ W,       // [NV, 1024]
    const float* __restrict__ b,       // [1024]
    const float* __restrict__ root,    // [32, 32]
    const float* __restrict__ bias,    // [32]
    float* __restrict__ hout)          // [N, 32]
{
    __shared__ float hb[4][256];
    const int lane = threadIdx.x & 63;
    const int o = lane & 31;
    const int half = lane >> 5;
    const int i0 = half * 16;
    const int w = threadIdx.x >> 6;
    float* hbw = &hb[w][0];
    const int n = blockIdx.x * 4 + w;   // wave-uniform

    float wreg[16][6], breg[16];
#pragma unroll
    for (int j = 0; j < 16; j++) {
#pragma unroll
        for (int v = 0; v < 6; v++) wreg[j][v] = W[v * 1024 + (i0 + j) * C + o];
        breg[j] = b[(i0 + j) * C + o];
    }

    const int beg = rowptr[n], end = rowptr[n + 1];
    float acc = 0.0f;

    for (int kb = beg; kb < end; kb += 8) {
        // 8 edge ids, clamped (uniform addresses -> scalar-friendly)
        int e[8];
#pragma unroll
        for (int k = 0; k < 8; k++) {
            int kk = kb + k;
            kk = (kk < end - 1) ? kk : (end - 1);
            e[k] = __builtin_amdgcn_readfirstlane(eid[kk]);
        }
        // this half's 4 edges (uniform-pair select)
        const int g0 = half ? e[4] : e[0];
        const int g1 = half ? e[5] : e[1];
        const int g2 = half ? e[6] : e[2];
        const int g3 = half ? e[7] : e[3];
        const int kbase = kb + half * 4;
        float4 hq;
        hq.x = (kbase + 0 < end) ? hprev[src[g0] * C + o] : 0.0f;
        hq.y = (kbase + 1 < end) ? hprev[src[g1] * C + o] : 0.0f;
        hq.z = (kbase + 2 < end) ? hprev[src[g2] * C + o] : 0.0f;
        hq.w = (kbase + 3 < end) ? hprev[src[g3] * C + o] : 0.0f;
        *(float4*)&hbw[half * 128 + o * 4] = hq;  // contiguous 1KB wave write

#pragma unroll
        for (int sub = 0; sub < 2; sub++) {
            float eaf[24];
#pragma unroll
            for (int k = 0; k < 4; k++) {
                const float* eap = ea + (size_t)e[sub * 4 + k] * NV;
#pragma unroll
                for (int v = 0; v < 6; v++) eaf[k * 6 + v] = eap[v];
            }
            float a0 = 0.0f, a1 = 0.0f, a2 = 0.0f, a3 = 0.0f;
#pragma unroll
            for (int j = 0; j < 16; j++) {
                const float4 hA = *(const float4*)&hbw[sub * 128 + (i0 + j) * 4];
                const float bb = breg[j];
                const float w0 = wreg[j][0], w1 = wreg[j][1], w2 = wreg[j][2];
                const float w3 = wreg[j][3], w4 = wreg[j][4], w5 = wreg[j][5];
                float t0 = bb, t1 = bb, t2 = bb, t3 = bb;
                t0 = fmaf(eaf[0],  w0, t0); t1 = fmaf(eaf[6],  w0, t1);
                t2 = fmaf(eaf[12], w0, t2); t3 = fmaf(eaf[18], w0, t3);
                t0 = fmaf(eaf[1],  w1, t0); t1 = fmaf(eaf[7],  w1, t1);
                t2 = fmaf(eaf[13], w1, t2); t3 = fmaf(eaf[19], w1, t3);
                t0 = fmaf(eaf[2],  w2, t0); t1 = fmaf(eaf[8],  w2, t1);
                t2 = fmaf(eaf[14], w2, t2); t3 = fmaf(eaf[20], w2, t3);
                t0 = fmaf(eaf[3],  w3, t0); t1 = fmaf(eaf[9],  w3, t1);
                t2 = fmaf(eaf[15], w3, t2); t3 = fmaf(eaf[21], w3, t3);
                t0 = fmaf(eaf[4],  w4, t0); t1 = fmaf(eaf[10], w4, t1);
                t2 = fmaf(eaf[16], w4, t2); t3 = fmaf(eaf[22], w4, t3);
                t0 = fmaf(eaf[5],  w5, t0); t1 = fmaf(eaf[11], w5, t1);
                t2 = fmaf(eaf[17], w5, t2); t3 = fmaf(eaf[23], w5, t3);
                a0 = fmaf(hA.x, fmaxf(t0, 0.0f), a0);
                a1 = fmaf(hA.y, fmaxf(t1, 0.0f), a1);
                a2 = fmaf(hA.z, fmaxf(t2, 0.0f), a2);
                a3 = fmaf(hA.w, fmaxf(t3, 0.0f), a3);
            }
            acc += (a0 + a1) + (a2 + a3);   // all edges share node n
        }
    }
    acc += __shfl_down(acc, 32);
    if (lane < 32) {
        const float inv = 1.0f / fmaxf((float)(end - beg), 1.0f);
        float r = fmaf(acc, inv, bias[o]);
#pragma unroll
        for (int i = 0; i < C; i++) r = fmaf(hprev[n * C + i], root[i * C + o], r);
        hout[n * C + o] = fmaxf(r, 0.0f);
    }
}

// ---- CBT: out[i,j] = sum_k |h[i,k]-h[j,k]| (proven)
__global__ __launch_bounds__(BLK) void cbt_kernel(const float* __restrict__ h,
                                                  float* __restrict__ out) {
    __shared__ float hj_s[64][33];
    __shared__ float hi_s[64 * 32];
    const int lane = threadIdx.x & 63;
    const int w = threadIdx.x >> 6;
    const int j0 = blockIdx.x * 64;
    const int i0 = blockIdx.y * 64;
    for (int t = threadIdx.x; t < 64 * 32; t += BLK) {
        hj_s[t >> 5][t & 31] = h[j0 * 32 + t];
        hi_s[t] = h[i0 * 32 + t];
    }
    __syncthreads();
    float hj[32];
#pragma unroll
    for (int k = 0; k < 32; k++) hj[k] = hj_s[lane][k];
    const int j = j0 + lane;
#pragma unroll 4
    for (int ii = w * 16; ii < w * 16 + 16; ii++) {
        float acc = 0.0f;
#pragma unroll
        for (int k = 0; k < 32; k++) acc += fabsf(hi_s[ii * 32 + k] - hj[k]);
        out[(size_t)(i0 + ii) * N_NODES + j] = acc;
    }
}

extern "C" void kernel_launch(void* const* d_in, const int* in_sizes, int n_in,
                              void* d_out, int out_size, void* d_ws, size_t ws_size,
                              hipStream_t stream) {
    const float* x         = (const float*)d_in[0];
    const float* edge_attr = (const float*)d_in[1];
    const int*   edge_idx  = (const int*)d_in[2];
    const float* W1 = (const float*)d_in[3];
    const float* b1 = (const float*)d_in[4];
    const float* root1 = (const float*)d_in[5];
    const float* bias1 = (const float*)d_in[6];
    const float* W2 = (const float*)d_in[7];
    const float* b2 = (const float*)d_in[8];
    const float* root2 = (const float*)d_in[9];
    const float* bias2 = (const float*)d_in[10];
    const float* W3 = (const float*)d_in[11];
    const float* b3 = (const float*)d_in[12];
    const float* root3 = (const float*)d_in[13];
    const float* bias3 = (const float*)d_in[14];

    const int* src = edge_idx;
    const int* dst = edge_idx + N_EDGES;

    int* wsi    = (int*)d_ws;
    int* cnt_i  = wsi;               // 2048
    int* cursor = wsi + 2048;        // 2048
    int* rowptr = wsi + 4096;        // 2049
    int* eid    = wsi + 6160;        // 65536
    float* h1   = (float*)(wsi + 6160 + 65536);
    float* h2   = h1 + N_NODES * C;
    float* h3   = h2 + N_NODES * C;

    // zero cnt_i + cursor (16 KB only)
    hipMemsetAsync(d_ws, 0, 4096 * sizeof(int), stream);

    // CSR build (dst shared by all layers)
    hist_kernel<<<N_EDGES / BLK, BLK, 0, stream>>>(dst, cnt_i);
    scan_kernel<<<1, 256, 0, stream>>>(cnt_i, rowptr);
    scatter_kernel<<<N_EDGES / BLK, BLK, 0, stream>>>(dst, rowptr, cursor, eid);

    // Layer 1 fused
    layer1_kernel<<<N_NODES / 4, BLK, 0, stream>>>(x, edge_attr, src, rowptr, eid,
                                                   W1, b1, root1, bias1, h1);
    // Layers 2/3 fused node-centric NNConv (no atomics, no msg)
    nnconv23_kernel<<<N_NODES / 4, BLK, 0, stream>>>(h1, edge_attr, src, rowptr, eid,
                                                     W2, b2, root2, bias2, h2);
    nnconv23_kernel<<<N_NODES / 4, BLK, 0, stream>>>(h2, edge_attr, src, rowptr, eid,
                                                     W3, b3, root3, bias3, h3);
    // CBT
    cbt_kernel<<<dim3(N_NODES / 64, N_NODES / 64), BLK, 0, stream>>>(h3, (float*)d_out);
}

// Round 13
// 167.790 us; speedup vs baseline: 1.2488x; 1.2488x over previous
//
#include <hip/hip_runtime.h>

#define N_NODES 2048
#define N_EDGES 65536
#define NV 6
#define C 32
#define BLK 256

// ---------------------------------------------------------------------------
// R13 == R10 exactly (measured best: 166.6 us). ws layout (floats):
//   cnt[2048] | sum1|sum2|sum3 [65536 each] | h1|h2|h3.
// memset zeroes cnt+sum1 (270 KB); sum2/sum3 zeroed inside edge1.
// Locked-in lessons: atomic scatter > CSR/msg/gather (R3,R9,R12);
// coop grid.sync ~50us/sync (R7); reg-W needs (256,2), cap->spill (R11);
// 4-group up-front h staging is the best e23 latency shape (R10).
// ---------------------------------------------------------------------------

// Layer 1 (in_c = 1), degree count fused (o==0 lane), sum2/3 zeroing fused.
__global__ void edge1_kernel(const float* __restrict__ x,
                             const float* __restrict__ ea,
                             const int* __restrict__ src,
                             const int* __restrict__ dst,
                             const float* __restrict__ W1,
                             const float* __restrict__ b1,
                             float* __restrict__ sum1,
                             float* __restrict__ sum23,   // sum2 base (2*N*C floats)
                             float* __restrict__ cnt) {
    int t = blockIdx.x * blockDim.x + threadIdx.x;
    if (t < 2 * N_NODES * C) sum23[t] = 0.0f;   // zero sum2+sum3
    int e = t >> 5, o = t & 31;
    if (e >= N_EDGES) return;
    const float* eap = ea + e * NV;
    float w = b1[o];
#pragma unroll
    for (int v = 0; v < NV; v++) w = fmaf(eap[v], W1[v * C + o], w);
    w = fmaxf(w, 0.0f);
    int d = dst[e];
    atomicAdd(&sum1[d * C + o], x[src[e]] * w);
    if (o == 0) atomicAdd(&cnt[d], 1.0f);
}

// Finalize a layer: h_out = relu(sum/max(cnt,1) + h_prev @ root + bias)
template <int IN_C>
__global__ void node_kernel(const float* __restrict__ sum,
                            const float* __restrict__ cnt,
                            const float* __restrict__ hprev,
                            const float* __restrict__ root,  // [IN_C, C]
                            const float* __restrict__ bias,  // [C]
                            float* __restrict__ hout) {
    int t = blockIdx.x * blockDim.x + threadIdx.x;  // N*C threads
    int n = t >> 5, o = t & 31;
    float inv = 1.0f / fmaxf(cnt[n], 1.0f);
    float acc = sum[t] * inv + bias[o];
#pragma unroll
    for (int i = 0; i < IN_C; i++) acc = fmaf(hprev[n * IN_C + i], root[i * C + o], acc);
    hout[t] = fmaxf(acc, 0.0f);
}

// Layers 2/3 (R10-proven): reg-W core + up-front 4-group h staging.
// lane l: o=l&31, half=l>>5, i-slice [half*16,+16); wreg[16][6]+breg[16]
// is exactly the lane's j-loop footprint. Wave owns groups wid+{0,2048,
// 4096,6144}; all 16 h-gather chains issue back-to-back up front (MLP),
// staged per-wave per-group in LDS (contiguous 1KB b128 writes, broadcast
// b128 reads -- 0 conflicts measured). unroll 2 overlaps ea loads with FMAs.
__global__ __launch_bounds__(BLK, 2) void edge23_kernel(
    const float* __restrict__ hprev,   // [N, 32]
    const float* __restrict__ ea,      // [E, 6]
    const int* __restrict__ src,
    const int* __restrict__ dst,
    const float* __restrict__ W,       // [NV, 1024]
    const float* __restrict__ b,       // [1024]
    float* __restrict__ sumout)        // [N, 32]
{
    __shared__ float hb[4][4][256];    // [wave][group][...] = 16 KB
    const int lane = threadIdx.x & 63;
    const int o = lane & 31;
    const int half = lane >> 5;
    const int i0 = half * 16;
    const int w = threadIdx.x >> 6;

    float wreg[16][6], breg[16];
#pragma unroll
    for (int j = 0; j < 16; j++) {
#pragma unroll
        for (int v = 0; v < 6; v++) wreg[j][v] = W[v * 1024 + (i0 + j) * C + o];
        breg[j] = b[(i0 + j) * C + o];
    }

    const int wid = (blockIdx.x * BLK + threadIdx.x) >> 6;  // 0..2047

    // ---- stage h[src] for all 4 groups up front ----
    int4 sqs[4];
#pragma unroll
    for (int i = 0; i < 4; i++)
        sqs[i] = *(const int4*)&src[(wid + i * 2048) * 8 + half * 4];
#pragma unroll
    for (int i = 0; i < 4; i++) {
        float4 hq;
        hq.x = hprev[sqs[i].x * C + o];
        hq.y = hprev[sqs[i].y * C + o];
        hq.z = hprev[sqs[i].z * C + o];
        hq.w = hprev[sqs[i].w * C + o];
        *(float4*)&hb[w][i][half * 128 + o * 4] = hq;  // contiguous 1KB wave write
    }

#pragma unroll 2
    for (int i = 0; i < 4; i++) {
        const int e0 = (wid + i * 2048) * 8;
        const float* hbw = &hb[w][i][0];
        const float4* eap4 = (const float4*)(ea + (size_t)e0 * NV);
        float accs[8];
#pragma unroll
        for (int sub = 0; sub < 2; sub++) {
            float eaf[24];
#pragma unroll
            for (int t = 0; t < 6; t++) *(float4*)&eaf[t * 4] = eap4[sub * 6 + t];
            float a0 = 0.0f, a1 = 0.0f, a2 = 0.0f, a3 = 0.0f;
#pragma unroll
            for (int j = 0; j < 16; j++) {
                const float4 hA = *(const float4*)&hbw[sub * 128 + (i0 + j) * 4];
                const float bb = breg[j];
                const float w0 = wreg[j][0], w1 = wreg[j][1], w2 = wreg[j][2];
                const float w3 = wreg[j][3], w4 = wreg[j][4], w5 = wreg[j][5];
                float t0 = bb, t1 = bb, t2 = bb, t3 = bb;
                t0 = fmaf(eaf[0],  w0, t0); t1 = fmaf(eaf[6],  w0, t1);
                t2 = fmaf(eaf[12], w0, t2); t3 = fmaf(eaf[18], w0, t3);
                t0 = fmaf(eaf[1],  w1, t0); t1 = fmaf(eaf[7],  w1, t1);
                t2 = fmaf(eaf[13], w1, t2); t3 = fmaf(eaf[19], w1, t3);
                t0 = fmaf(eaf[2],  w2, t0); t1 = fmaf(eaf[8],  w2, t1);
                t2 = fmaf(eaf[14], w2, t2); t3 = fmaf(eaf[20], w2, t3);
                t0 = fmaf(eaf[3],  w3, t0); t1 = fmaf(eaf[9],  w3, t1);
                t2 = fmaf(eaf[15], w3, t2); t3 = fmaf(eaf[21], w3, t3);
                t0 = fmaf(eaf[4],  w4, t0); t1 = fmaf(eaf[10], w4, t1);
                t2 = fmaf(eaf[16], w4, t2); t3 = fmaf(eaf[22], w4, t3);
                t0 = fmaf(eaf[5],  w5, t0); t1 = fmaf(eaf[11], w5, t1);
                t2 = fmaf(eaf[17], w5, t2); t3 = fmaf(eaf[23], w5, t3);
                a0 = fmaf(hA.x, fmaxf(t0, 0.0f), a0);
                a1 = fmaf(hA.y, fmaxf(t1, 0.0f), a1);
                a2 = fmaf(hA.z, fmaxf(t2, 0.0f), a2);
                a3 = fmaf(hA.w, fmaxf(t3, 0.0f), a3);
            }
            accs[sub * 4 + 0] = a0; accs[sub * 4 + 1] = a1;
            accs[sub * 4 + 2] = a2; accs[sub * 4 + 3] = a3;
        }
#pragma unroll
        for (int k = 0; k < 8; k++) accs[k] += __shfl_down(accs[k], 32);

        const int4 dA = *(const int4*)&dst[e0];
        const int4 dB = *(const int4*)&dst[e0 + 4];
        if (lane < 32) {
            atomicAdd(&sumout[dA.x * C + o], accs[0]);
            atomicAdd(&sumout[dA.y * C + o], accs[1]);
            atomicAdd(&sumout[dA.z * C + o], accs[2]);
            atomicAdd(&sumout[dA.w * C + o], accs[3]);
            atomicAdd(&sumout[dB.x * C + o], accs[4]);
            atomicAdd(&sumout[dB.y * C + o], accs[5]);
            atomicAdd(&sumout[dB.z * C + o], accs[6]);
            atomicAdd(&sumout[dB.w * C + o], accs[7]);
        }
    }
}

// CBT: out[i,j] = sum_k |h[i,k]-h[j,k]|. 256-thread blocks, 64x64 tiles.
__global__ __launch_bounds__(BLK) void cbt_kernel(const float* __restrict__ h,
                                                  float* __restrict__ out) {
    __shared__ float hj_s[64][33];
    __shared__ float hi_s[64 * 32];
    const int lane = threadIdx.x & 63;
    const int w = threadIdx.x >> 6;
    const int j0 = blockIdx.x * 64;
    const int i0 = blockIdx.y * 64;
    for (int t = threadIdx.x; t < 64 * 32; t += BLK) {
        hj_s[t >> 5][t & 31] = h[j0 * 32 + t];
        hi_s[t] = h[i0 * 32 + t];
    }
    __syncthreads();
    float hj[32];
#pragma unroll
    for (int k = 0; k < 32; k++) hj[k] = hj_s[lane][k];
    const int j = j0 + lane;
#pragma unroll 4
    for (int ii = w * 16; ii < w * 16 + 16; ii++) {
        float acc = 0.0f;
#pragma unroll
        for (int k = 0; k < 32; k++) acc += fabsf(hi_s[ii * 32 + k] - hj[k]);
        out[(size_t)(i0 + ii) * N_NODES + j] = acc;
    }
}

extern "C" void kernel_launch(void* const* d_in, const int* in_sizes, int n_in,
                              void* d_out, int out_size, void* d_ws, size_t ws_size,
                              hipStream_t stream) {
    const float* x         = (const float*)d_in[0];
    const float* edge_attr = (const float*)d_in[1];
    const int*   edge_idx  = (const int*)d_in[2];
    const float* W1 = (const float*)d_in[3];
    const float* b1 = (const float*)d_in[4];
    const float* root1 = (const float*)d_in[5];
    const float* bias1 = (const float*)d_in[6];
    const float* W2 = (const float*)d_in[7];
    const float* b2 = (const float*)d_in[8];
    const float* root2 = (const float*)d_in[9];
    const float* bias2 = (const float*)d_in[10];
    const float* W3 = (const float*)d_in[11];
    const float* b3 = (const float*)d_in[12];
    const float* root3 = (const float*)d_in[13];
    const float* bias3 = (const float*)d_in[14];

    const int* src = edge_idx;            // row 0
    const int* dst = edge_idx + N_EDGES;  // row 1

    float* ws   = (float*)d_ws;
    float* cnt  = ws;
    float* sum1 = ws + N_NODES;
    float* sum2 = sum1 + N_NODES * C;
    float* sum3 = sum2 + N_NODES * C;
    float* h1   = sum3 + N_NODES * C;
    float* h2   = h1 + N_NODES * C;
    float* h3   = h2 + N_NODES * C;

    // zero cnt + sum1 only (270 KB); sum2/sum3 zeroed inside edge1
    hipMemsetAsync(d_ws, 0, (size_t)(N_NODES + N_NODES * C) * sizeof(float), stream);

    // Layer 1 (degree count + sum2/3 zeroing fused)
    edge1_kernel<<<(N_EDGES * C) / BLK, BLK, 0, stream>>>(x, edge_attr, src, dst,
                                                          W1, b1, sum1, sum2, cnt);
    node_kernel<1><<<(N_NODES * C) / BLK, BLK, 0, stream>>>(sum1, cnt, x, root1, bias1, h1);

    // Layer 2
    edge23_kernel<<<512, BLK, 0, stream>>>(h1, edge_attr, src, dst, W2, b2, sum2);
    node_kernel<C><<<(N_NODES * C) / BLK, BLK, 0, stream>>>(sum2, cnt, h1, root2, bias2, h2);

    // Layer 3
    edge23_kernel<<<512, BLK, 0, stream>>>(h2, edge_attr, src, dst, W3, b3, sum3);
    node_kernel<C><<<(N_NODES * C) / BLK, BLK, 0, stream>>>(sum3, cnt, h2, root3, bias3, h3);

    // CBT
    cbt_kernel<<<dim3(N_NODES / 64, N_NODES / 64), BLK, 0, stream>>>(h3, (float*)d_out);
}